// Round 7
// baseline (79.242 us; speedup 1.0000x reference)
//
#include <hip/hip_runtime.h>

#define G_ 1024
#define DIN_ 3072
#define B_ 8192
#define TB 4          // rows per block; output tile = 4*3072 floats = 48 KiB = xs
#define TPB 512
#define GPT 2         // consecutive groups per thread

// ---------------------------------------------------------------------------
// Fused single kernel, LDS-staged OUTPUT.
// out[b,g,m] = K + cx0*x0 + cx1*x1 + cx2*x2 + cq01*x0x1 + cq02*x0x2 + cq12*x1x2
// where x_i = x[b, conn[g,i]]; the 7 coeffs per (g,m) fold the soft-gate,
// the 6 Fredkin permutations, and the softmax weights.
//
// Schedule per block:
//   0) param loads (conn/sel/wg for 2 consecutive groups)
//   1) issue 6x global_load_lds (4 rows -> 48 KiB LDS, linear dest)
//   2) coefficient recompute in registers  <- covers stage latency
//   3) barrier
//   4) all 24 LDS gathers -> registers
//   5) barrier (xs fully consumed -> reuse as output stage)
//   6) per row: 42 FMA, ds_write 6 floats (3x float2)
//   7) barrier; 6x fully-contiguous global_store_dwordx4 per thread
// Every 64 B output line is covered by exactly ONE store instruction ->
// no partial-line write amplification at 3 blocks/CU (the round-6 killer).
// 48 KiB LDS, VGPR <= 85 via __launch_bounds__(512,6) -> 3 blocks/CU.
// ---------------------------------------------------------------------------
__global__ __launch_bounds__(TPB, 6) void fredkin_fused_kernel(
    const float* __restrict__ x, const int* __restrict__ conn,
    const float* __restrict__ sel, const float* __restrict__ wg,
    float* __restrict__ out)
{
    __shared__ float xs[TB * DIN_];   // 48 KiB; input tile, then output tile
    const int t = threadIdx.x;
    const int row0 = blockIdx.x * TB;

    // ---- phase 0: param loads first ----
    const int g0 = t * GPT;
    int   cc[GPT][3];
    float ss[GPT][3];
    float ww[GPT][6];
#pragma unroll
    for (int gi = 0; gi < GPT; ++gi) {
#pragma unroll
        for (int i = 0; i < 3; ++i) cc[gi][i] = conn[(g0 + gi) * 3 + i];
#pragma unroll
        for (int i = 0; i < 3; ++i) ss[gi][i] = sel[(g0 + gi) * 3 + i];
#pragma unroll
        for (int p = 0; p < 6; ++p) ww[gi][p] = wg[(g0 + gi) * 6 + p];
    }

    // ---- phase 1: issue direct-to-LDS stage (6 x 16 B per thread) ----
    const float4* xv = (const float4*)(x + (size_t)row0 * DIN_);
    float4* sv = (float4*)xs;
#pragma unroll
    for (int i = 0; i < (TB * DIN_ / 4) / TPB; ++i)   // 6 iters
        __builtin_amdgcn_global_load_lds(
            (const __attribute__((address_space(1))) void*)(xv + t + i * TPB),
            (__attribute__((address_space(3))) void*)(sv + t + i * TPB),
            16, 0, 0);

    // ---- phase 2: coefficient recompute (covers stage latency) ----
    float CF[GPT][3][7];   // per m: K, cx0, cx1, cx2, cq01, cq02, cq12
#pragma unroll
    for (int gi = 0; gi < GPT; ++gi) {
        float u[3], v[3];
#pragma unroll
        for (int i = 0; i < 3; ++i) {
            float s = ss[gi][i];
            float C = s / (1.0f + fabsf(s));
            float a = fabsf(C);
            u[i] = 1.0f - a;
            v[i] = 0.5f * (C + a);
        }

        float w[6];
        float mx = -1e30f;
#pragma unroll
        for (int p = 0; p < 6; ++p) mx = fmaxf(mx, ww[gi][p]);
        float sum = 0.0f;
#pragma unroll
        for (int p = 0; p < 6; ++p) { w[p] = __expf(ww[gi][p] - mx); sum += w[p]; }
        float inv = 1.0f / sum;
#pragma unroll
        for (int p = 0; p < 6; ++p) w[p] *= inv;

        // itertools.permutations(range(3)); signals:
        // m0 = a ; m1 = c + ab - ac ; m2 = b - ab + ac  (a,b,c = permuted gated)
        const int P[6][3] = {{0,1,2},{0,2,1},{1,0,2},{1,2,0},{2,0,1},{2,1,0}};
        float L[3][3] = {{0.f,0.f,0.f},{0.f,0.f,0.f},{0.f,0.f,0.f}};
        float Q[3][3] = {{0.f,0.f,0.f},{0.f,0.f,0.f},{0.f,0.f,0.f}};
#pragma unroll
        for (int p = 0; p < 6; ++p) {
            int i0 = P[p][0], i1 = P[p][1], i2 = P[p][2];
            float wp = w[p];
            int p01 = i0 + i1 - 1;   // pair idx (i,j)->i+j-1, i<j
            int p02 = i0 + i2 - 1;
            L[0][i0] += wp;
            L[1][i2] += wp; Q[1][p01] += wp; Q[1][p02] -= wp;
            L[2][i1] += wp; Q[2][p01] -= wp; Q[2][p02] += wp;
        }

        // substitute gated_i = u_i*x_i + v_i -> x-space coefficients
#pragma unroll
        for (int m = 0; m < 3; ++m) {
            CF[gi][m][0] = L[m][0]*v[0] + L[m][1]*v[1] + L[m][2]*v[2]
                         + Q[m][0]*v[0]*v[1] + Q[m][1]*v[0]*v[2] + Q[m][2]*v[1]*v[2];
            CF[gi][m][1] = u[0]*(L[m][0] + Q[m][0]*v[1] + Q[m][1]*v[2]);
            CF[gi][m][2] = u[1]*(L[m][1] + Q[m][0]*v[0] + Q[m][2]*v[2]);
            CF[gi][m][3] = u[2]*(L[m][2] + Q[m][1]*v[0] + Q[m][2]*v[1]);
            CF[gi][m][4] = Q[m][0]*u[0]*u[1];
            CF[gi][m][5] = Q[m][1]*u[0]*u[2];
            CF[gi][m][6] = Q[m][2]*u[1]*u[2];
        }
    }

    // ---- phase 3: stage complete ----
    __syncthreads();

    // ---- phase 4: ALL gathers up front (xs fully consumed after this) ----
    float gx[GPT][3][TB];
#pragma unroll
    for (int r = 0; r < TB; ++r)
#pragma unroll
        for (int gi = 0; gi < GPT; ++gi) {
            gx[gi][0][r] = xs[r * DIN_ + cc[gi][0]];
            gx[gi][1][r] = xs[r * DIN_ + cc[gi][1]];
            gx[gi][2][r] = xs[r * DIN_ + cc[gi][2]];
        }

    // ---- phase 5: xs is dead; reuse as output staging ----
    __syncthreads();

#pragma unroll
    for (int r = 0; r < TB; ++r) {
        float o[GPT * 3];
#pragma unroll
        for (int gi = 0; gi < GPT; ++gi) {
            const float x0 = gx[gi][0][r], x1 = gx[gi][1][r], x2 = gx[gi][2][r];
            const float p01 = x0 * x1, p02 = x0 * x2, p12 = x1 * x2;
#pragma unroll
            for (int m = 0; m < 3; ++m) {
                o[gi * 3 + m] = CF[gi][m][0]
                              + CF[gi][m][1]*x0 + CF[gi][m][2]*x1 + CF[gi][m][3]*x2
                              + CF[gi][m][4]*p01 + CF[gi][m][5]*p02 + CF[gi][m][6]*p12;
            }
        }
        // stage row-major into LDS: row r, cols 6t..6t+5 (8 B aligned)
        float2* lp = (float2*)(xs + r * DIN_ + 6 * t);
        lp[0] = make_float2(o[0], o[1]);
        lp[1] = make_float2(o[2], o[3]);
        lp[2] = make_float2(o[4], o[5]);
    }

    // ---- phase 7: coalesced streaming store of the 48 KiB tile ----
    __syncthreads();
    const float4* ls = (const float4*)xs;
    float4* op = (float4*)(out + (size_t)row0 * (3 * G_));   // 3*G_ == DIN_
#pragma unroll
    for (int i = 0; i < (TB * DIN_ / 4) / TPB; ++i)   // 6 iters, 1024 B/wave each
        op[t + i * TPB] = ls[t + i * TPB];
}

extern "C" void kernel_launch(void* const* d_in, const int* in_sizes, int n_in,
                              void* d_out, int out_size, void* d_ws, size_t ws_size,
                              hipStream_t stream) {
    const float* x    = (const float*)d_in[0];
    const int*   conn = (const int*)d_in[1];
    const float* sel  = (const float*)d_in[2];
    const float* wg   = (const float*)d_in[3];
    float* out = (float*)d_out;

    hipLaunchKernelGGL(fredkin_fused_kernel, dim3(B_ / TB), dim3(TPB), 0, stream,
                       x, conn, sel, wg, out);
}

// Round 8
// 39.459 us; speedup vs baseline: 2.0082x; 2.0082x over previous
//
#include <hip/hip_runtime.h>

#define G_ 1024
#define DIN_ 3072
#define B_ 8192
#define TB 4          // rows staged per block (48 KiB LDS)
#define TPB 512
#define GPT 2         // consecutive groups per thread

typedef float v2f __attribute__((ext_vector_type(2)));

// ---------------------------------------------------------------------------
// Fused single kernel (round-5 structure, the measured best: 39 us).
// out[b,g,m] = K + cx0*x0 + cx1*x1 + cx2*x2 + cq01*x0x1 + cq02*x0x2 + cq12*x1x2
// where x_i = x[b, conn[g,i]]; the 7 coeffs per (g,m) fold the soft-gate,
// the 6 Fredkin permutations, and the softmax weights.
//
// Round-8 single change: NON-TEMPORAL output stores. out is write-once per
// replay and never re-read; nt keeps the 96 MiB out stream from evicting the
// (re-read every replay) 96 MiB x working set out of L3.
//
// Schedule per block:
//   1) issue 6x global_load_lds (TB rows -> 48 KiB LDS, linear dest)
//   2) recompute 2 groups' coefficients in registers (covers stage latency /
//      cross-block overlap at 2 blocks/CU)
//   3) __syncthreads
//   4) 4 rows x { 6 LDS gathers, 42 FMA, 24 B contiguous nt store }
// 512 thr, VGPR ~44, 48 KiB LDS, __launch_bounds__(512,4) -> 2 blocks/CU
// (the R6 experiment showed 3 blocks/CU thrashes L2: WRITE 98->151 MB).
// ---------------------------------------------------------------------------
__global__ __launch_bounds__(TPB, 4) void fredkin_fused_kernel(
    const float* __restrict__ x, const int* __restrict__ conn,
    const float* __restrict__ sel, const float* __restrict__ wg,
    float* __restrict__ out)
{
    __shared__ float xs[TB * DIN_];   // 48 KiB
    const int t = threadIdx.x;
    const int row0 = blockIdx.x * TB;

    // ---- phase 1: issue direct-to-LDS stage (6 x 16 B per thread) ----
    const float4* xv = (const float4*)(x + (size_t)row0 * DIN_);
    float4* sv = (float4*)xs;
#pragma unroll
    for (int i = 0; i < (TB * DIN_ / 4) / TPB; ++i)   // 6 iters
        __builtin_amdgcn_global_load_lds(
            (const __attribute__((address_space(1))) void*)(xv + t + i * TPB),
            (__attribute__((address_space(3))) void*)(sv + t + i * TPB),
            16, 0, 0);

    // ---- phase 2: coefficient recompute for GPT consecutive groups ----
    int   cc[GPT][3];
    float CF[GPT][3][7];   // per m: K, cx0, cx1, cx2, cq01, cq02, cq12
#pragma unroll
    for (int gi = 0; gi < GPT; ++gi) {
        const int g = t * GPT + gi;

        float u[3], v[3];
#pragma unroll
        for (int i = 0; i < 3; ++i) {
            cc[gi][i] = conn[g * 3 + i];
            float s = sel[g * 3 + i];
            float C = s / (1.0f + fabsf(s));
            float a = fabsf(C);
            u[i] = 1.0f - a;
            v[i] = 0.5f * (C + a);
        }

        // softmax over 6 permutation weights
        float w[6];
        float mx = -1e30f;
#pragma unroll
        for (int p = 0; p < 6; ++p) mx = fmaxf(mx, wg[g * 6 + p]);
        float sum = 0.0f;
#pragma unroll
        for (int p = 0; p < 6; ++p) { w[p] = __expf(wg[g * 6 + p] - mx); sum += w[p]; }
        float inv = 1.0f / sum;
#pragma unroll
        for (int p = 0; p < 6; ++p) w[p] *= inv;

        // itertools.permutations(range(3)); signals:
        // m0 = a ; m1 = c + ab - ac ; m2 = b - ab + ac  (a,b,c = permuted gated)
        const int P[6][3] = {{0,1,2},{0,2,1},{1,0,2},{1,2,0},{2,0,1},{2,1,0}};
        float L[3][3] = {{0.f,0.f,0.f},{0.f,0.f,0.f},{0.f,0.f,0.f}};
        float Q[3][3] = {{0.f,0.f,0.f},{0.f,0.f,0.f},{0.f,0.f,0.f}};
#pragma unroll
        for (int p = 0; p < 6; ++p) {
            int i0 = P[p][0], i1 = P[p][1], i2 = P[p][2];
            float wp = w[p];
            int p01 = i0 + i1 - 1;   // pair idx (i,j)->i+j-1, i<j
            int p02 = i0 + i2 - 1;
            L[0][i0] += wp;
            L[1][i2] += wp; Q[1][p01] += wp; Q[1][p02] -= wp;
            L[2][i1] += wp; Q[2][p01] -= wp; Q[2][p02] += wp;
        }

        // substitute gated_i = u_i*x_i + v_i -> x-space coefficients
#pragma unroll
        for (int m = 0; m < 3; ++m) {
            CF[gi][m][0] = L[m][0]*v[0] + L[m][1]*v[1] + L[m][2]*v[2]
                         + Q[m][0]*v[0]*v[1] + Q[m][1]*v[0]*v[2] + Q[m][2]*v[1]*v[2];
            CF[gi][m][1] = u[0]*(L[m][0] + Q[m][0]*v[1] + Q[m][1]*v[2]);
            CF[gi][m][2] = u[1]*(L[m][1] + Q[m][0]*v[0] + Q[m][2]*v[2]);
            CF[gi][m][3] = u[2]*(L[m][2] + Q[m][1]*v[0] + Q[m][2]*v[1]);
            CF[gi][m][4] = Q[m][0]*u[0]*u[1];
            CF[gi][m][5] = Q[m][1]*u[0]*u[2];
            CF[gi][m][6] = Q[m][2]*u[1]*u[2];
        }
    }

    // ---- phase 3: barrier (stage landed under phase 2 / other block) ----
    __syncthreads();

    // ---- phase 4: evaluate TB rows ----
#pragma unroll
    for (int r = 0; r < TB; ++r) {
        const float* xb = xs + r * DIN_;
        // all 6 gathers independent, issued together
        float gx[GPT][3];
#pragma unroll
        for (int gi = 0; gi < GPT; ++gi) {
            gx[gi][0] = xb[cc[gi][0]];
            gx[gi][1] = xb[cc[gi][1]];
            gx[gi][2] = xb[cc[gi][2]];
        }
        float o[GPT * 3];
#pragma unroll
        for (int gi = 0; gi < GPT; ++gi) {
            const float x0 = gx[gi][0], x1 = gx[gi][1], x2 = gx[gi][2];
            const float p01 = x0 * x1, p02 = x0 * x2, p12 = x1 * x2;
#pragma unroll
            for (int m = 0; m < 3; ++m) {
                o[gi * 3 + m] = CF[gi][m][0]
                              + CF[gi][m][1]*x0 + CF[gi][m][2]*x1 + CF[gi][m][3]*x2
                              + CF[gi][m][4]*p01 + CF[gi][m][5]*p02 + CF[gi][m][6]*p12;
            }
        }
        // 24 B contiguous per lane -> wave writes 1536 B contiguous; nt.
        v2f* op = (v2f*)(out + (size_t)(row0 + r) * (3 * G_) + (size_t)t * (3 * GPT));
        v2f s0; s0[0] = o[0]; s0[1] = o[1];
        v2f s1; s1[0] = o[2]; s1[1] = o[3];
        v2f s2; s2[0] = o[4]; s2[1] = o[5];
        __builtin_nontemporal_store(s0, op + 0);
        __builtin_nontemporal_store(s1, op + 1);
        __builtin_nontemporal_store(s2, op + 2);
    }
}

extern "C" void kernel_launch(void* const* d_in, const int* in_sizes, int n_in,
                              void* d_out, int out_size, void* d_ws, size_t ws_size,
                              hipStream_t stream) {
    const float* x    = (const float*)d_in[0];
    const int*   conn = (const int*)d_in[1];
    const float* sel  = (const float*)d_in[2];
    const float* wg   = (const float*)d_in[3];
    float* out = (float*)d_out;

    hipLaunchKernelGGL(fredkin_fused_kernel, dim3(B_ / TB), dim3(TPB), 0, stream,
                       x, conn, sel, wg, out);
}